// Round 5
// baseline (259.483 us; speedup 1.0000x reference)
//
#include <hip/hip_runtime.h>
#include <cstdint>
#include <cstddef>

#define D_MODEL 512
#define SEQ_T 2048
#define NHEADS 8
#define HDIM 64

typedef __attribute__((ext_vector_type(8))) short bf16x8;
typedef __attribute__((ext_vector_type(4))) float f32x4;

__device__ __forceinline__ unsigned short f2bf(float f) {
  unsigned int u = __float_as_uint(f);
  u += 0x7FFFu + ((u >> 16) & 1u);
  return (unsigned short)(u >> 16);
}

// pack two f32 -> two bf16 in one uint (round-half-up via +0x8000, v_perm)
__device__ __forceinline__ unsigned int pack_bf16(float lo, float hi) {
  unsigned int a = __float_as_uint(lo) + 0x8000u;
  unsigned int b = __float_as_uint(hi) + 0x8000u;
  return __builtin_amdgcn_perm(b, a, 0x07060302u);
}

// Q pre-scaled by 1/sqrt(64) * log2(e) so softmax runs in exp2 domain.
#define QSCALE 0.18033688011112043f
// fixed softmax shift: p = exp2(s - SSHIFT); common factor cancels in O/l.
#define SSHIFT 16.0f

// async global->LDS, 16B per lane. LDS dest = wave-uniform base + lane*16.
__device__ __forceinline__ void async_lds16(const unsigned short* g,
                                            unsigned short* l) {
  __builtin_amdgcn_global_load_lds(
      (const __attribute__((address_space(1))) void*)g,
      (__attribute__((address_space(3))) void*)l, 16, 0, 0);
}

// ---------------------------------------------------------------------------
// Prep 0: elementwise fp32 -> bf16 (n multiple of 2048)
// ---------------------------------------------------------------------------
__global__ __launch_bounds__(256) void cast_bf16_kernel(
    const float* __restrict__ in, unsigned short* __restrict__ outp) {
  int i = (blockIdx.x * 256 + threadIdx.x) * 8;
  float4 a = *(const float4*)(in + i);
  float4 b = *(const float4*)(in + i + 4);
  ushort4 lo = {f2bf(a.x), f2bf(a.y), f2bf(a.z), f2bf(a.w)};
  ushort4 hi = {f2bf(b.x), f2bf(b.y), f2bf(b.z), f2bf(b.w)};
  *(ushort4*)(outp + i) = lo;
  *(ushort4*)(outp + i + 4) = hi;
}

// ---------------------------------------------------------------------------
// Prep 1: cast + transpose. in [R][C] fp32 -> out [C][R] bf16. 64x64 tiles.
// ---------------------------------------------------------------------------
__global__ __launch_bounds__(256) void transpose_cast_kernel(
    const float* __restrict__ in, unsigned short* __restrict__ outp, int R,
    int C) {
  __shared__ float tile[64][65];
  const int c0 = blockIdx.x * 64, r0 = blockIdx.y * 64;
  for (int i = threadIdx.x; i < 64 * 64; i += 256) {
    int r = i >> 6, c = i & 63;
    tile[r][c] = in[(size_t)(r0 + r) * C + c0 + c];
  }
  __syncthreads();
  for (int i = threadIdx.x; i < 64 * 64; i += 256) {
    int c = i >> 6, r = i & 63;
    outp[(size_t)(c0 + c) * R + r0 + r] = f2bf(tile[r][c]);
  }
}

// ---------------------------------------------------------------------------
// Kernel 1: QKV projection, bf16 MFMA (m97 structure, unchanged).
// ---------------------------------------------------------------------------
__global__ __launch_bounds__(256) void gemm_qkv_mfma(
    const unsigned short* __restrict__ xb, const unsigned short* __restrict__ Wt,
    const float* __restrict__ bias, unsigned short* __restrict__ Qb,
    unsigned short* __restrict__ Kb, unsigned short* __restrict__ Vtb) {
  __shared__ unsigned short As[128 * 32];
  __shared__ unsigned short Bs[128 * 32];
  const int tid = threadIdx.x;
  const int w = tid >> 6, lane = tid & 63;
  const int quad = lane >> 4, l15 = lane & 15;
  const int wm = w >> 1, wn = w & 1;
  const int m0 = blockIdx.x * 128, n0 = blockIdx.y * 128;

  const unsigned short* ga = xb + (size_t)(m0 + (tid >> 2)) * 512 + (tid & 3) * 8;
  const unsigned short* gb = Wt + (size_t)(n0 + (tid >> 2)) * 512 + (tid & 3) * 8;
  unsigned short* lA = As + tid * 8;
  unsigned short* lB = Bs + tid * 8;

  f32x4 acc[4][4] = {};
  for (int k0 = 0; k0 < 512; k0 += 32) {
    async_lds16(ga + k0, lA);
    async_lds16(ga + 64 * 512 + k0, lA + 2048);
    async_lds16(gb + k0, lB);
    async_lds16(gb + 64 * 512 + k0, lB + 2048);
    __syncthreads();
    bf16x8 af[4], bfr[4];
#pragma unroll
    for (int mb = 0; mb < 4; ++mb)
      af[mb] = *(const bf16x8*)&As[(wm * 64 + mb * 16 + l15) * 32 + quad * 8];
#pragma unroll
    for (int nb = 0; nb < 4; ++nb)
      bfr[nb] = *(const bf16x8*)&Bs[(wn * 64 + nb * 16 + l15) * 32 + quad * 8];
#pragma unroll
    for (int mb = 0; mb < 4; ++mb)
#pragma unroll
      for (int nb = 0; nb < 4; ++nb)
        acc[mb][nb] = __builtin_amdgcn_mfma_f32_16x16x32_bf16(
            af[mb], bfr[nb], acc[mb][nb], 0, 0, 0);
    __syncthreads();
  }

  const int cbase = n0 + wn * 64;
  const int three = cbase >> 9;
  const int h = (cbase >> 6) & 7;
  const int bh = ((m0 >> 11) << 3) + h;
  const int t0 = (m0 & 2047) + wm * 64;
  float bv[4];
#pragma unroll
  for (int nb = 0; nb < 4; ++nb) bv[nb] = bias[cbase + nb * 16 + l15];

  if (three == 2) {
#pragma unroll
    for (int mb = 0; mb < 4; ++mb)
#pragma unroll
      for (int nb = 0; nb < 4; ++nb) {
        int trow = t0 + mb * 16 + quad * 4;
        ushort4 v = {f2bf(acc[mb][nb][0] + bv[nb]), f2bf(acc[mb][nb][1] + bv[nb]),
                     f2bf(acc[mb][nb][2] + bv[nb]), f2bf(acc[mb][nb][3] + bv[nb])};
        *(ushort4*)(Vtb + ((size_t)bh * HDIM + nb * 16 + l15) * SEQ_T + trow) = v;
      }
  } else {
    unsigned short* dst = three ? Kb : Qb;
    const float sc = three ? 1.0f : QSCALE;
#pragma unroll
    for (int mb = 0; mb < 4; ++mb)
#pragma unroll
      for (int nb = 0; nb < 4; ++nb)
#pragma unroll
        for (int r = 0; r < 4; ++r) {
          int trow = t0 + mb * 16 + quad * 4 + r;
          dst[((size_t)bh * SEQ_T + trow) * HDIM + nb * 16 + l15] =
              f2bf((acc[mb][nb][r] + bv[nb]) * sc);
        }
  }
}

// ---------------------------------------------------------------------------
// Kernel 2 (v3): causal flash attention, transposed-score, FIXED-SHIFT
// softmax (p = exp2(s-16); no max tracking, no rescale, no in-loop shfl).
// No K/V LDS staging: fragments load global->VGPR directly (L1 serves the
// 4 sibling waves); NO barriers anywhere. LDS = wave-private P round-trip
// only. Grid: 1024 blocks (one 64-row q-tile each), XCD-swizzled so each
// bh's blocks share one XCD L2, longest q-tiles dispatched first.
// ---------------------------------------------------------------------------
__global__ __launch_bounds__(256) void attn_mfma3(
    const unsigned short* __restrict__ Qb, const unsigned short* __restrict__ Kb,
    const unsigned short* __restrict__ Vtb, unsigned short* __restrict__ AOb) {
  __shared__ __align__(16) unsigned short Pt[4][16][72];
  const int tid = threadIdx.x;
  const int w = tid >> 6, lane = tid & 63;
  const int quad = lane >> 4, l15 = lane & 15;

  // block -> (bh, qt): bid&7 selects XCD; each XCD owns 4 bh values.
  const int bid = blockIdx.x;
  const int xcd = bid & 7;
  const int i = bid >> 3;             // 0..127
  const int bh = xcd + 8 * (i & 3);
  const int qt = 31 - (i >> 2);       // longest-first

  const unsigned short* kbase = Kb + (size_t)bh * SEQ_T * HDIM;
  const unsigned short* vbase = Vtb + (size_t)bh * HDIM * SEQ_T;

  // Q B-fragments (wave w covers q rows qt*64 + w*16 + l15)
  const unsigned short* qp =
      Qb + ((size_t)bh * SEQ_T + qt * 64 + w * 16 + l15) * HDIM + quad * 8;
  bf16x8 qf0 = *(const bf16x8*)qp;
  bf16x8 qf1 = *(const bf16x8*)(qp + 32);

  f32x4 O[4] = {{0.f, 0.f, 0.f, 0.f}, {0.f, 0.f, 0.f, 0.f},
                {0.f, 0.f, 0.f, 0.f}, {0.f, 0.f, 0.f, 0.f}};
  float l_i = 0.f;
  const int q_rel = w * 16 + l15;

  auto do_tile = [&](int kt, bool diag) {
    // K fragments: A[m=key16=l15][k=d], direct from global
    const unsigned short* kp = kbase + ((size_t)(kt * 64) + l15) * 64 + quad * 8;
    bf16x8 kf0[4], kf1[4];
#pragma unroll
    for (int nb = 0; nb < 4; ++nb) {
      kf0[nb] = *(const bf16x8*)(kp + nb * 16 * 64);
      kf1[nb] = *(const bf16x8*)(kp + nb * 16 * 64 + 32);
    }
    // V fragments: A[m=dv=l15][k=key], direct from global (issued early)
    const unsigned short* vp = vbase + (size_t)l15 * SEQ_T + kt * 64 + quad * 8;
    bf16x8 vf0[4], vf1[4];
#pragma unroll
    for (int nbd = 0; nbd < 4; ++nbd) {
      vf0[nbd] = *(const bf16x8*)(vp + (size_t)nbd * 16 * SEQ_T);
      vf1[nbd] = *(const bf16x8*)(vp + (size_t)nbd * 16 * SEQ_T + 32);
    }

    // S^T = K . Q^T
    f32x4 S[4];
#pragma unroll
    for (int nb = 0; nb < 4; ++nb) {
      f32x4 z = {0.f, 0.f, 0.f, 0.f};
      z = __builtin_amdgcn_mfma_f32_16x16x32_bf16(kf0[nb], qf0, z, 0, 0, 0);
      S[nb] = __builtin_amdgcn_mfma_f32_16x16x32_bf16(kf1[nb], qf1, z, 0, 0, 0);
    }

    // p = exp2(s - 16); accumulate per-lane l; pack to bf16; stash in LDS
#pragma unroll
    for (int nb = 0; nb < 4; ++nb) {
      float pp[4];
#pragma unroll
      for (int r = 0; r < 4; ++r) {
        float p = __builtin_amdgcn_exp2f(S[nb][r] - SSHIFT);
        if (diag) {
          int key_rel = nb * 16 + quad * 4 + r;
          if (key_rel > q_rel) p = 0.f;
        }
        pp[r] = p;
        l_i += p;
      }
      uint2 pk = {pack_bf16(pp[0], pp[1]), pack_bf16(pp[2], pp[3])};
      *(uint2*)&Pt[w][l15][nb * 16 + quad * 4] = pk;
    }

    // O^T += V^T . P^T   (P via wave-private LDS, no barrier needed)
    const unsigned short* pr = &Pt[w][l15][quad * 8];
    bf16x8 pb0 = *(const bf16x8*)pr;
    bf16x8 pb1 = *(const bf16x8*)(pr + 32);
#pragma unroll
    for (int nbd = 0; nbd < 4; ++nbd) {
      O[nbd] = __builtin_amdgcn_mfma_f32_16x16x32_bf16(vf0[nbd], pb0, O[nbd],
                                                       0, 0, 0);
      O[nbd] = __builtin_amdgcn_mfma_f32_16x16x32_bf16(vf1[nbd], pb1, O[nbd],
                                                       0, 0, 0);
    }
  };

  for (int kt = 0; kt < qt; ++kt) do_tile(kt, false);
  do_tile(qt, true);

  // merge per-lane l across the 4 quads (once), normalize, write AO bf16
  float lt = l_i;
  lt += __shfl_xor(lt, 16);
  lt += __shfl_xor(lt, 32);
  float inv = 1.0f / lt;
  const int bb = bh >> 3, h = bh & 7;
  int qrow = qt * 64 + q_rel;
  unsigned short* dst = AOb + ((size_t)bb * SEQ_T + qrow) * D_MODEL + (h << 6);
#pragma unroll
  for (int nbd = 0; nbd < 4; ++nbd) {
    ushort4 o4 = {f2bf(O[nbd][0] * inv), f2bf(O[nbd][1] * inv),
                  f2bf(O[nbd][2] * inv), f2bf(O[nbd][3] * inv)};
    *(ushort4*)(dst + nbd * 16 + quad * 4) = o4;
  }
}

// ---------------------------------------------------------------------------
// Kernel 3: output projection, bf16 MFMA (unchanged).
// ---------------------------------------------------------------------------
__global__ __launch_bounds__(256) void gemm_out_mfma(
    const unsigned short* __restrict__ AOb, const unsigned short* __restrict__ Wot,
    const float* __restrict__ bias, float* __restrict__ out) {
  __shared__ unsigned short As[128 * 32];
  __shared__ unsigned short Bs[128 * 32];
  const int tid = threadIdx.x;
  const int w = tid >> 6, lane = tid & 63;
  const int quad = lane >> 4, l15 = lane & 15;
  const int wm = w >> 1, wn = w & 1;
  const int m0 = blockIdx.x * 128, n0 = blockIdx.y * 128;

  const unsigned short* ga = AOb + (size_t)(m0 + (tid >> 2)) * 512 + (tid & 3) * 8;
  const unsigned short* gb = Wot + (size_t)(n0 + (tid >> 2)) * 512 + (tid & 3) * 8;
  unsigned short* lA = As + tid * 8;
  unsigned short* lB = Bs + tid * 8;

  f32x4 acc[4][4] = {};
  for (int k0 = 0; k0 < 512; k0 += 32) {
    async_lds16(ga + k0, lA);
    async_lds16(ga + 64 * 512 + k0, lA + 2048);
    async_lds16(gb + k0, lB);
    async_lds16(gb + 64 * 512 + k0, lB + 2048);
    __syncthreads();
    bf16x8 af[4], bfr[4];
#pragma unroll
    for (int mb = 0; mb < 4; ++mb)
      af[mb] = *(const bf16x8*)&As[(wm * 64 + mb * 16 + l15) * 32 + quad * 8];
#pragma unroll
    for (int nb = 0; nb < 4; ++nb)
      bfr[nb] = *(const bf16x8*)&Bs[(wn * 64 + nb * 16 + l15) * 32 + quad * 8];
#pragma unroll
    for (int mb = 0; mb < 4; ++mb)
#pragma unroll
      for (int nb = 0; nb < 4; ++nb)
        acc[mb][nb] = __builtin_amdgcn_mfma_f32_16x16x32_bf16(
            af[mb], bfr[nb], acc[mb][nb], 0, 0, 0);
    __syncthreads();
  }

  const int cbase = n0 + wn * 64;
  const int rbase = m0 + wm * 64;
  float bv[4];
#pragma unroll
  for (int nb = 0; nb < 4; ++nb) bv[nb] = bias[cbase + nb * 16 + l15];
#pragma unroll
  for (int mb = 0; mb < 4; ++mb)
#pragma unroll
    for (int nb = 0; nb < 4; ++nb)
#pragma unroll
      for (int r = 0; r < 4; ++r)
        out[(size_t)(rbase + mb * 16 + quad * 4 + r) * 512 + cbase + nb * 16 +
            l15] = acc[mb][nb][r] + bv[nb];
}

// ---------------------------------------------------------------------------
extern "C" void kernel_launch(void* const* d_in, const int* in_sizes, int n_in,
                              void* d_out, int out_size, void* d_ws,
                              size_t ws_size, hipStream_t stream) {
  const float* x     = (const float*)d_in[0];
  const float* W_qkv = (const float*)d_in[1];
  const float* b_qkv = (const float*)d_in[2];
  const float* W_out = (const float*)d_in[3];
  const float* b_out = (const float*)d_in[4];
  float* out = (float*)d_out;

  const size_t NX = (size_t)4 * SEQ_T * D_MODEL;        // 4,194,304
  unsigned short* xb   = (unsigned short*)d_ws;          // [8192][512]
  unsigned short* Wqkt = xb + NX;                        // [1536][512]
  unsigned short* Wot  = Wqkt + (size_t)1536 * 512;      // [512][512]
  unsigned short* Qb   = Wot + (size_t)512 * 512;        // [bh][t][64]
  unsigned short* Kb   = Qb + NX;
  unsigned short* Vtb  = Kb + NX;                        // [bh][dv][t]
  unsigned short* AOb  = Vtb + NX;                       // [8192][512]

  cast_bf16_kernel<<<NX / 2048, 256, 0, stream>>>(x, xb);
  transpose_cast_kernel<<<dim3(24, 8), 256, 0, stream>>>(W_qkv, Wqkt, 512, 1536);
  transpose_cast_kernel<<<dim3(8, 8), 256, 0, stream>>>(W_out, Wot, 512, 512);

  gemm_qkv_mfma<<<dim3(64, 12), 256, 0, stream>>>(xb, Wqkt, b_qkv, Qb, Kb, Vtb);
  attn_mfma3<<<dim3(1024), 256, 0, stream>>>(Qb, Kb, Vtb, AOb);
  gemm_out_mfma<<<dim3(64, 4), 256, 0, stream>>>(AOb, Wot, b_out, out);
}

// Round 6
// 157.674 us; speedup vs baseline: 1.6457x; 1.6457x over previous
//
#include <hip/hip_runtime.h>
#include <cstdint>
#include <cstddef>

#define D_MODEL 512
#define SEQ_T 2048
#define NHEADS 8
#define HDIM 64

typedef __attribute__((ext_vector_type(8))) short bf16x8;
typedef __attribute__((ext_vector_type(4))) float f32x4;

__device__ __forceinline__ unsigned short f2bf(float f) {
  unsigned int u = __float_as_uint(f);
  u += 0x7FFFu + ((u >> 16) & 1u);
  return (unsigned short)(u >> 16);
}

// pack two f32 -> two bf16 in one uint (round via +0x8000, v_perm)
__device__ __forceinline__ unsigned int pack_bf16(float lo, float hi) {
  unsigned int a = __float_as_uint(lo) + 0x8000u;
  unsigned int b = __float_as_uint(hi) + 0x8000u;
  return __builtin_amdgcn_perm(b, a, 0x07060302u);
}

// Q pre-scaled by 1/sqrt(64) * log2(e) so softmax runs in exp2 domain.
#define QSCALE 0.18033688011112043f
// fixed softmax shift: p = exp2(s - SSHIFT); common factor cancels in O/l.
#define SSHIFT 16.0f

// async global->LDS, 16B per lane. LDS dest = wave-uniform base + lane*16.
__device__ __forceinline__ void async_lds16(const unsigned short* g,
                                            unsigned short* l) {
  __builtin_amdgcn_global_load_lds(
      (const __attribute__((address_space(1))) void*)g,
      (__attribute__((address_space(3))) void*)l, 16, 0, 0);
}

// ---------------------------------------------------------------------------
// Fused prep: [0,2048) cast x -> bf16; [2048,2240) transpose W_qkv;
// [2240,2304) transpose W_out. (one launch instead of three)
// ---------------------------------------------------------------------------
__global__ __launch_bounds__(256) void prep_kernel(
    const float* __restrict__ x, const float* __restrict__ W_qkv,
    const float* __restrict__ W_out, unsigned short* __restrict__ xb,
    unsigned short* __restrict__ Wqkt, unsigned short* __restrict__ Wot) {
  __shared__ float tile[64][65];
  const int bid = blockIdx.x;
  if (bid < 2048) {
    int i = (bid * 256 + threadIdx.x) * 8;
    float4 a = *(const float4*)(x + i);
    float4 b = *(const float4*)(x + i + 4);
    ushort4 lo = {f2bf(a.x), f2bf(a.y), f2bf(a.z), f2bf(a.w)};
    ushort4 hi = {f2bf(b.x), f2bf(b.y), f2bf(b.z), f2bf(b.w)};
    *(ushort4*)(xb + i) = lo;
    *(ushort4*)(xb + i + 4) = hi;
    return;
  }
  const float* src;
  unsigned short* dst;
  int R = 512, C, c0, r0;
  if (bid < 2048 + 192) {
    int t = bid - 2048;
    C = 1536; c0 = (t % 24) * 64; r0 = (t / 24) * 64;
    src = W_qkv; dst = Wqkt;
  } else {
    int t = bid - 2240;
    C = 512; c0 = (t & 7) * 64; r0 = (t >> 3) * 64;
    src = W_out; dst = Wot;
  }
  for (int i = threadIdx.x; i < 64 * 64; i += 256) {
    int r = i >> 6, c = i & 63;
    tile[r][c] = src[(size_t)(r0 + r) * C + c0 + c];
  }
  __syncthreads();
  for (int i = threadIdx.x; i < 64 * 64; i += 256) {
    int c = i >> 6, r = i & 63;
    dst[(size_t)(c0 + c) * R + r0 + r] = f2bf(tile[r][c]);
  }
}

// ---------------------------------------------------------------------------
// Kernel 1: QKV projection, bf16 MFMA (m97 structure, unchanged).
// ---------------------------------------------------------------------------
__global__ __launch_bounds__(256) void gemm_qkv_mfma(
    const unsigned short* __restrict__ xb, const unsigned short* __restrict__ Wt,
    const float* __restrict__ bias, unsigned short* __restrict__ Qb,
    unsigned short* __restrict__ Kb, unsigned short* __restrict__ Vtb) {
  __shared__ unsigned short As[128 * 32];
  __shared__ unsigned short Bs[128 * 32];
  const int tid = threadIdx.x;
  const int w = tid >> 6, lane = tid & 63;
  const int quad = lane >> 4, l15 = lane & 15;
  const int wm = w >> 1, wn = w & 1;
  const int m0 = blockIdx.x * 128, n0 = blockIdx.y * 128;

  const unsigned short* ga = xb + (size_t)(m0 + (tid >> 2)) * 512 + (tid & 3) * 8;
  const unsigned short* gb = Wt + (size_t)(n0 + (tid >> 2)) * 512 + (tid & 3) * 8;
  unsigned short* lA = As + tid * 8;
  unsigned short* lB = Bs + tid * 8;

  f32x4 acc[4][4] = {};
  for (int k0 = 0; k0 < 512; k0 += 32) {
    async_lds16(ga + k0, lA);
    async_lds16(ga + 64 * 512 + k0, lA + 2048);
    async_lds16(gb + k0, lB);
    async_lds16(gb + 64 * 512 + k0, lB + 2048);
    __syncthreads();
    bf16x8 af[4], bfr[4];
#pragma unroll
    for (int mb = 0; mb < 4; ++mb)
      af[mb] = *(const bf16x8*)&As[(wm * 64 + mb * 16 + l15) * 32 + quad * 8];
#pragma unroll
    for (int nb = 0; nb < 4; ++nb)
      bfr[nb] = *(const bf16x8*)&Bs[(wn * 64 + nb * 16 + l15) * 32 + quad * 8];
#pragma unroll
    for (int mb = 0; mb < 4; ++mb)
#pragma unroll
      for (int nb = 0; nb < 4; ++nb)
        acc[mb][nb] = __builtin_amdgcn_mfma_f32_16x16x32_bf16(
            af[mb], bfr[nb], acc[mb][nb], 0, 0, 0);
    __syncthreads();
  }

  const int cbase = n0 + wn * 64;
  const int three = cbase >> 9;
  const int h = (cbase >> 6) & 7;
  const int bh = ((m0 >> 11) << 3) + h;
  const int t0 = (m0 & 2047) + wm * 64;
  float bv[4];
#pragma unroll
  for (int nb = 0; nb < 4; ++nb) bv[nb] = bias[cbase + nb * 16 + l15];

  if (three == 2) {
#pragma unroll
    for (int mb = 0; mb < 4; ++mb)
#pragma unroll
      for (int nb = 0; nb < 4; ++nb) {
        int trow = t0 + mb * 16 + quad * 4;
        ushort4 v = {f2bf(acc[mb][nb][0] + bv[nb]), f2bf(acc[mb][nb][1] + bv[nb]),
                     f2bf(acc[mb][nb][2] + bv[nb]), f2bf(acc[mb][nb][3] + bv[nb])};
        *(ushort4*)(Vtb + ((size_t)bh * HDIM + nb * 16 + l15) * SEQ_T + trow) = v;
      }
  } else {
    unsigned short* dst = three ? Kb : Qb;
    const float sc = three ? 1.0f : QSCALE;
#pragma unroll
    for (int mb = 0; mb < 4; ++mb)
#pragma unroll
      for (int nb = 0; nb < 4; ++nb)
#pragma unroll
        for (int r = 0; r < 4; ++r) {
          int trow = t0 + mb * 16 + quad * 4 + r;
          dst[((size_t)bh * SEQ_T + trow) * HDIM + nb * 16 + l15] =
              f2bf((acc[mb][nb][r] + bv[nb]) * sc);
        }
  }
}

// ---------------------------------------------------------------------------
// Kernel 2 (v4): causal flash attention.
//  - r4's double-buffered LDS staging (register prefetch, 1 barrier/tile)
//  - r5's fixed-shift softmax (p = exp2(s-16): no max/alpha/rescale/shfl)
//  - XOR-swizzled LDS (16B chunk ^= row&7), stride 64: staging writes and
//    b128 fragment reads are <=2-way bank-aliased (free per m136)
//  - grid 1024 (one 64-row q-tile per block), XCD-swizzled, longest-first
// ---------------------------------------------------------------------------
__global__ __launch_bounds__(256, 4) void attn_mfma4(
    const unsigned short* __restrict__ Qb, const unsigned short* __restrict__ Kb,
    const unsigned short* __restrict__ Vtb, unsigned short* __restrict__ AOb) {
  __shared__ __align__(16) unsigned short Ks[2][64 * 64];
  __shared__ __align__(16) unsigned short Vs[2][64 * 64];
  __shared__ __align__(16) unsigned short Pt[4][16 * 64];
  const int tid = threadIdx.x;
  const int w = tid >> 6, lane = tid & 63;
  const int quad = lane >> 4, l15 = lane & 15;

  // block -> (bh, qt): bid&7 selects XCD; longest q-tiles first.
  const int bid = blockIdx.x;
  const int xcd = bid & 7;
  const int ii = bid >> 3;
  const int bh = xcd + 8 * (ii & 3);
  const int qt = 31 - (ii >> 2);

  const unsigned short* kbase = Kb + (size_t)bh * SEQ_T * HDIM;
  const unsigned short* vbase = Vtb + (size_t)bh * HDIM * SEQ_T;
  const int sr = tid >> 3;                    // staging row 0..31
  const int lc = tid & 7;                     // logical 16B chunk
  const int scol = lc * 8;
  const int swc = (lc ^ (sr & 7)) * 8;        // swizzled chunk offset

  // Q B-fragments
  const unsigned short* qp =
      Qb + ((size_t)bh * SEQ_T + qt * 64 + w * 16 + l15) * HDIM + quad * 8;
  bf16x8 qf0 = *(const bf16x8*)qp;
  bf16x8 qf1 = *(const bf16x8*)(qp + 32);

  f32x4 O[4] = {{0.f, 0.f, 0.f, 0.f}, {0.f, 0.f, 0.f, 0.f},
                {0.f, 0.f, 0.f, 0.f}, {0.f, 0.f, 0.f, 0.f}};
  float l_i = 0.f;
  const int q_rel = w * 16 + l15;
  const int r7 = l15 & 7;   // row&7 for all fragment rows (nb*16+l15)

  // stage tile 0
  uint4 rk0, rk1, rv0, rv1;
  {
    const unsigned short* kp = kbase + (size_t)sr * 64 + scol;
    rk0 = *(const uint4*)kp;
    rk1 = *(const uint4*)(kp + 32 * 64);
    const unsigned short* vp = vbase + (size_t)sr * SEQ_T + scol;
    rv0 = *(const uint4*)vp;
    rv1 = *(const uint4*)(vp + 32 * SEQ_T);
  }
  *(uint4*)&Ks[0][sr * 64 + swc] = rk0;
  *(uint4*)&Ks[0][(sr + 32) * 64 + swc] = rk1;
  *(uint4*)&Vs[0][sr * 64 + swc] = rv0;
  *(uint4*)&Vs[0][(sr + 32) * 64 + swc] = rv1;
  __syncthreads();

  for (int i = 0; i <= qt; ++i) {
    const int cur = i & 1;
    const bool diag = (i == qt);

    // prefetch next tile global -> regs
    if (i < qt) {
      const int nkt = i + 1;
      const unsigned short* kp = kbase + (size_t)(nkt * 64 + sr) * 64 + scol;
      rk0 = *(const uint4*)kp;
      rk1 = *(const uint4*)(kp + 32 * 64);
      const unsigned short* vp = vbase + (size_t)sr * SEQ_T + nkt * 64 + scol;
      rv0 = *(const uint4*)vp;
      rv1 = *(const uint4*)(vp + 32 * SEQ_T);
    }

    // ---- S^T = K . Q^T ----
    const int nb_lim = diag ? (w + 1) : 4;
    f32x4 S[4];
#pragma unroll
    for (int nb = 0; nb < 4; ++nb) {
      if (nb < nb_lim) {
        const int row = nb * 16 + l15;
        const unsigned short* k0p = &Ks[cur][row * 64 + ((quad ^ r7) * 8)];
        const unsigned short* k1p = &Ks[cur][row * 64 + (((quad + 4) ^ r7) * 8)];
        f32x4 z = {0.f, 0.f, 0.f, 0.f};
        z = __builtin_amdgcn_mfma_f32_16x16x32_bf16(*(const bf16x8*)k0p, qf0,
                                                    z, 0, 0, 0);
        S[nb] = __builtin_amdgcn_mfma_f32_16x16x32_bf16(*(const bf16x8*)k1p,
                                                        qf1, z, 0, 0, 0);
      }
    }

    // ---- fixed-shift softmax: p = exp2(s - 16), per-lane l ----
#pragma unroll
    for (int nb = 0; nb < 4; ++nb) {
      if (nb < nb_lim) {
        float pp[4];
#pragma unroll
        for (int r = 0; r < 4; ++r) {
          float p = __builtin_amdgcn_exp2f(S[nb][r] - SSHIFT);
          if (diag) {
            int key_rel = nb * 16 + quad * 4 + r;
            if (key_rel > q_rel) p = 0.f;
          }
          pp[r] = p;
          l_i += p;
        }
        int c = 2 * nb + (quad >> 1);
        uint2 pk = {pack_bf16(pp[0], pp[1]), pack_bf16(pp[2], pp[3])};
        *(uint2*)&Pt[w][l15 * 64 + ((c ^ r7) * 8) + (quad & 1) * 4] = pk;
      } else {
        int c = 2 * nb + (quad >> 1);
        uint2 z2 = {0u, 0u};
        *(uint2*)&Pt[w][l15 * 64 + ((c ^ r7) * 8) + (quad & 1) * 4] = z2;
      }
    }

    // ---- O^T += V^T . P^T ----
    const int kpv = (!diag || w >= 2) ? 2 : 1;
    bf16x8 pb0 = *(const bf16x8*)&Pt[w][l15 * 64 + ((quad ^ r7) * 8)];
    bf16x8 pb1 = *(const bf16x8*)&Pt[w][l15 * 64 + (((quad + 4) ^ r7) * 8)];
#pragma unroll
    for (int nbd = 0; nbd < 4; ++nbd) {
      const int row = nbd * 16 + l15;
      const unsigned short* v0p = &Vs[cur][row * 64 + ((quad ^ r7) * 8)];
      O[nbd] = __builtin_amdgcn_mfma_f32_16x16x32_bf16(*(const bf16x8*)v0p,
                                                       pb0, O[nbd], 0, 0, 0);
      if (kpv == 2) {
        const unsigned short* v1p =
            &Vs[cur][row * 64 + (((quad + 4) ^ r7) * 8)];
        O[nbd] = __builtin_amdgcn_mfma_f32_16x16x32_bf16(*(const bf16x8*)v1p,
                                                         pb1, O[nbd], 0, 0, 0);
      }
    }

    // ---- store prefetched tile into alternate buffer, 1 barrier/tile ----
    if (i < qt) {
      const int nxt = cur ^ 1;
      *(uint4*)&Ks[nxt][sr * 64 + swc] = rk0;
      *(uint4*)&Ks[nxt][(sr + 32) * 64 + swc] = rk1;
      *(uint4*)&Vs[nxt][sr * 64 + swc] = rv0;
      *(uint4*)&Vs[nxt][(sr + 32) * 64 + swc] = rv1;
      __syncthreads();
    }
  }

  // merge per-lane l across quads, normalize, write AO bf16
  float lt = l_i;
  lt += __shfl_xor(lt, 16);
  lt += __shfl_xor(lt, 32);
  float inv = 1.0f / lt;
  const int bb = bh >> 3, h = bh & 7;
  int qrow = qt * 64 + q_rel;
  unsigned short* dst = AOb + ((size_t)bb * SEQ_T + qrow) * D_MODEL + (h << 6);
#pragma unroll
  for (int nbd = 0; nbd < 4; ++nbd) {
    ushort4 o4 = {f2bf(O[nbd][0] * inv), f2bf(O[nbd][1] * inv),
                  f2bf(O[nbd][2] * inv), f2bf(O[nbd][3] * inv)};
    *(ushort4*)(dst + nbd * 16 + quad * 4) = o4;
  }
}

// ---------------------------------------------------------------------------
// Kernel 3: output projection, bf16 MFMA (unchanged).
// ---------------------------------------------------------------------------
__global__ __launch_bounds__(256) void gemm_out_mfma(
    const unsigned short* __restrict__ AOb, const unsigned short* __restrict__ Wot,
    const float* __restrict__ bias, float* __restrict__ out) {
  __shared__ unsigned short As[128 * 32];
  __shared__ unsigned short Bs[128 * 32];
  const int tid = threadIdx.x;
  const int w = tid >> 6, lane = tid & 63;
  const int quad = lane >> 4, l15 = lane & 15;
  const int wm = w >> 1, wn = w & 1;
  const int m0 = blockIdx.x * 128, n0 = blockIdx.y * 128;

  const unsigned short* ga = AOb + (size_t)(m0 + (tid >> 2)) * 512 + (tid & 3) * 8;
  const unsigned short* gb = Wot + (size_t)(n0 + (tid >> 2)) * 512 + (tid & 3) * 8;
  unsigned short* lA = As + tid * 8;
  unsigned short* lB = Bs + tid * 8;

  f32x4 acc[4][4] = {};
  for (int k0 = 0; k0 < 512; k0 += 32) {
    async_lds16(ga + k0, lA);
    async_lds16(ga + 64 * 512 + k0, lA + 2048);
    async_lds16(gb + k0, lB);
    async_lds16(gb + 64 * 512 + k0, lB + 2048);
    __syncthreads();
    bf16x8 af[4], bfr[4];
#pragma unroll
    for (int mb = 0; mb < 4; ++mb)
      af[mb] = *(const bf16x8*)&As[(wm * 64 + mb * 16 + l15) * 32 + quad * 8];
#pragma unroll
    for (int nb = 0; nb < 4; ++nb)
      bfr[nb] = *(const bf16x8*)&Bs[(wn * 64 + nb * 16 + l15) * 32 + quad * 8];
#pragma unroll
    for (int mb = 0; mb < 4; ++mb)
#pragma unroll
      for (int nb = 0; nb < 4; ++nb)
        acc[mb][nb] = __builtin_amdgcn_mfma_f32_16x16x32_bf16(
            af[mb], bfr[nb], acc[mb][nb], 0, 0, 0);
    __syncthreads();
  }

  const int cbase = n0 + wn * 64;
  const int rbase = m0 + wm * 64;
  float bv[4];
#pragma unroll
  for (int nb = 0; nb < 4; ++nb) bv[nb] = bias[cbase + nb * 16 + l15];
#pragma unroll
  for (int mb = 0; mb < 4; ++mb)
#pragma unroll
    for (int nb = 0; nb < 4; ++nb)
#pragma unroll
      for (int r = 0; r < 4; ++r)
        out[(size_t)(rbase + mb * 16 + quad * 4 + r) * 512 + cbase + nb * 16 +
            l15] = acc[mb][nb][r] + bv[nb];
}

// ---------------------------------------------------------------------------
extern "C" void kernel_launch(void* const* d_in, const int* in_sizes, int n_in,
                              void* d_out, int out_size, void* d_ws,
                              size_t ws_size, hipStream_t stream) {
  const float* x     = (const float*)d_in[0];
  const float* W_qkv = (const float*)d_in[1];
  const float* b_qkv = (const float*)d_in[2];
  const float* W_out = (const float*)d_in[3];
  const float* b_out = (const float*)d_in[4];
  float* out = (float*)d_out;

  const size_t NX = (size_t)4 * SEQ_T * D_MODEL;        // 4,194,304
  unsigned short* xb   = (unsigned short*)d_ws;          // [8192][512]
  unsigned short* Wqkt = xb + NX;                        // [1536][512]
  unsigned short* Wot  = Wqkt + (size_t)1536 * 512;      // [512][512]
  unsigned short* Qb   = Wot + (size_t)512 * 512;        // [bh][t][64]
  unsigned short* Kb   = Qb + NX;
  unsigned short* Vtb  = Kb + NX;                        // [bh][dv][t]
  unsigned short* AOb  = Vtb + NX;                       // [8192][512]

  prep_kernel<<<2304, 256, 0, stream>>>(x, W_qkv, W_out, xb, Wqkt, Wot);
  gemm_qkv_mfma<<<dim3(64, 12), 256, 0, stream>>>(xb, Wqkt, b_qkv, Qb, Kb, Vtb);
  attn_mfma4<<<dim3(1024), 256, 0, stream>>>(Qb, Kb, Vtb, AOb);
  gemm_out_mfma<<<dim3(64, 4), 256, 0, stream>>>(AOb, Wot, b_out, out);
}

// Round 7
// 132.835 us; speedup vs baseline: 1.9534x; 1.1870x over previous
//
#include <hip/hip_runtime.h>
#include <cstdint>
#include <cstddef>

#define D_MODEL 512
#define SEQ_T 2048
#define NHEADS 8
#define HDIM 64

typedef __attribute__((ext_vector_type(8))) short bf16x8;
typedef __attribute__((ext_vector_type(4))) float f32x4;

__device__ __forceinline__ unsigned short f2bf(float f) {
  unsigned int u = __float_as_uint(f);
  u += 0x7FFFu + ((u >> 16) & 1u);
  return (unsigned short)(u >> 16);
}

// pack two f32 -> two bf16 in one uint (round via +0x8000, v_perm)
__device__ __forceinline__ unsigned int pack_bf16(float lo, float hi) {
  unsigned int a = __float_as_uint(lo) + 0x8000u;
  unsigned int b = __float_as_uint(hi) + 0x8000u;
  return __builtin_amdgcn_perm(b, a, 0x07060302u);
}

// Q pre-scaled by 1/sqrt(64) * log2(e) so softmax runs in exp2 domain.
#define QSCALE 0.18033688011112043f
// fixed softmax shift: p = exp2(s - SSHIFT); common factor cancels in O/l.
#define SSHIFT 16.0f

// async global->LDS, 16B per lane. LDS dest = wave-uniform base + lane*16.
__device__ __forceinline__ void async_lds16(const unsigned short* g,
                                            unsigned short* l) {
  __builtin_amdgcn_global_load_lds(
      (const __attribute__((address_space(1))) void*)g,
      (__attribute__((address_space(3))) void*)l, 16, 0, 0);
}

// ---------------------------------------------------------------------------
// Fused prep: [0,2048) cast x -> bf16; [2048,2240) transpose W_qkv;
// [2240,2304) transpose W_out.
// ---------------------------------------------------------------------------
__global__ __launch_bounds__(256) void prep_kernel(
    const float* __restrict__ x, const float* __restrict__ W_qkv,
    const float* __restrict__ W_out, unsigned short* __restrict__ xb,
    unsigned short* __restrict__ Wqkt, unsigned short* __restrict__ Wot) {
  __shared__ float tile[64][65];
  const int bid = blockIdx.x;
  if (bid < 2048) {
    int i = (bid * 256 + threadIdx.x) * 8;
    float4 a = *(const float4*)(x + i);
    float4 b = *(const float4*)(x + i + 4);
    ushort4 lo = {f2bf(a.x), f2bf(a.y), f2bf(a.z), f2bf(a.w)};
    ushort4 hi = {f2bf(b.x), f2bf(b.y), f2bf(b.z), f2bf(b.w)};
    *(ushort4*)(xb + i) = lo;
    *(ushort4*)(xb + i + 4) = hi;
    return;
  }
  const float* src;
  unsigned short* dst;
  int R = 512, C, c0, r0;
  if (bid < 2048 + 192) {
    int t = bid - 2048;
    C = 1536; c0 = (t % 24) * 64; r0 = (t / 24) * 64;
    src = W_qkv; dst = Wqkt;
  } else {
    int t = bid - 2240;
    C = 512; c0 = (t & 7) * 64; r0 = (t >> 3) * 64;
    src = W_out; dst = Wot;
  }
  for (int i = threadIdx.x; i < 64 * 64; i += 256) {
    int r = i >> 6, c = i & 63;
    tile[r][c] = src[(size_t)(r0 + r) * C + c0 + c];
  }
  __syncthreads();
  for (int i = threadIdx.x; i < 64 * 64; i += 256) {
    int c = i >> 6, r = i & 63;
    dst[(size_t)(c0 + c) * R + r0 + r] = f2bf(tile[r][c]);
  }
}

// ---------------------------------------------------------------------------
// Kernel 1: QKV projection, bf16 MFMA. 128x128 tile, BK=64 (8 K-iters),
// XOR-swizzled LDS (16B chunk ^= row&7) -> conflict-free b128 fragment reads.
// Epilogue: Q -> bf16 [bh][d][t] TRANSPOSED packed ushort4 (pre-scaled);
// V -> bf16 [bh][dv][t] packed ushort4; K -> bf16 [bh][t][d] scalar.
// ---------------------------------------------------------------------------
__global__ __launch_bounds__(256) void gemm_qkv_mfma(
    const unsigned short* __restrict__ xb, const unsigned short* __restrict__ Wt,
    const float* __restrict__ bias, unsigned short* __restrict__ Qtb,
    unsigned short* __restrict__ Kb, unsigned short* __restrict__ Vtb) {
  __shared__ unsigned short As[128 * 64];
  __shared__ unsigned short Bs[128 * 64];
  const int tid = threadIdx.x;
  const int w = tid >> 6, lane = tid & 63;
  const int quad = lane >> 4, l15 = lane & 15;
  const int wm = w >> 1, wn = w & 1;
  const int m0 = blockIdx.x * 128, n0 = blockIdx.y * 128;

  const int srow = tid >> 3;                   // 0..31
  const int schunk = (tid & 7) ^ (srow & 7);   // logical chunk loaded
  const unsigned short* ga = xb + (size_t)(m0 + srow) * 512 + schunk * 8;
  const unsigned short* gb = Wt + (size_t)(n0 + srow) * 512 + schunk * 8;
  unsigned short* lA = As + tid * 8;
  unsigned short* lB = Bs + tid * 8;

  f32x4 acc[4][4] = {};
  for (int k0 = 0; k0 < 512; k0 += 64) {
#pragma unroll
    for (int rr = 0; rr < 4; ++rr) {
      async_lds16(ga + (size_t)rr * 32 * 512 + k0, lA + rr * 2048);
      async_lds16(gb + (size_t)rr * 32 * 512 + k0, lB + rr * 2048);
    }
    __syncthreads();
    bf16x8 af[4][2], bfr[4][2];
#pragma unroll
    for (int mb = 0; mb < 4; ++mb) {
      int row = wm * 64 + mb * 16 + l15;
#pragma unroll
      for (int kk = 0; kk < 2; ++kk) {
        int slot = (kk * 4 + quad) ^ (row & 7);
        af[mb][kk] = *(const bf16x8*)&As[row * 64 + slot * 8];
      }
    }
#pragma unroll
    for (int nb = 0; nb < 4; ++nb) {
      int row = wn * 64 + nb * 16 + l15;
#pragma unroll
      for (int kk = 0; kk < 2; ++kk) {
        int slot = (kk * 4 + quad) ^ (row & 7);
        bfr[nb][kk] = *(const bf16x8*)&Bs[row * 64 + slot * 8];
      }
    }
#pragma unroll
    for (int mb = 0; mb < 4; ++mb)
#pragma unroll
      for (int nb = 0; nb < 4; ++nb) {
        acc[mb][nb] = __builtin_amdgcn_mfma_f32_16x16x32_bf16(
            af[mb][0], bfr[nb][0], acc[mb][nb], 0, 0, 0);
        acc[mb][nb] = __builtin_amdgcn_mfma_f32_16x16x32_bf16(
            af[mb][1], bfr[nb][1], acc[mb][nb], 0, 0, 0);
      }
    __syncthreads();
  }

  const int cbase = n0 + wn * 64;
  const int three = cbase >> 9;          // 0:Q 1:K 2:V
  const int h = (cbase >> 6) & 7;
  const int bh = ((m0 >> 11) << 3) + h;
  const int t0 = (m0 & 2047) + wm * 64;
  float bv[4];
#pragma unroll
  for (int nb = 0; nb < 4; ++nb) bv[nb] = bias[cbase + nb * 16 + l15];

  if (three == 0) {
    // Q transposed [bh][d][t], pre-scaled, packed along t
#pragma unroll
    for (int mb = 0; mb < 4; ++mb)
#pragma unroll
      for (int nb = 0; nb < 4; ++nb) {
        int trow = t0 + mb * 16 + quad * 4;
        ushort4 v = {f2bf((acc[mb][nb][0] + bv[nb]) * QSCALE),
                     f2bf((acc[mb][nb][1] + bv[nb]) * QSCALE),
                     f2bf((acc[mb][nb][2] + bv[nb]) * QSCALE),
                     f2bf((acc[mb][nb][3] + bv[nb]) * QSCALE)};
        *(ushort4*)(Qtb + ((size_t)bh * HDIM + nb * 16 + l15) * SEQ_T + trow) = v;
      }
  } else if (three == 2) {
    // V transposed [bh][dv][t], packed along t
#pragma unroll
    for (int mb = 0; mb < 4; ++mb)
#pragma unroll
      for (int nb = 0; nb < 4; ++nb) {
        int trow = t0 + mb * 16 + quad * 4;
        ushort4 v = {f2bf(acc[mb][nb][0] + bv[nb]), f2bf(acc[mb][nb][1] + bv[nb]),
                     f2bf(acc[mb][nb][2] + bv[nb]), f2bf(acc[mb][nb][3] + bv[nb])};
        *(ushort4*)(Vtb + ((size_t)bh * HDIM + nb * 16 + l15) * SEQ_T + trow) = v;
      }
  } else {
    // K row-major [bh][t][d] (required for attn A-fragment contiguity)
#pragma unroll
    for (int mb = 0; mb < 4; ++mb)
#pragma unroll
      for (int nb = 0; nb < 4; ++nb)
#pragma unroll
        for (int r = 0; r < 4; ++r) {
          int trow = t0 + mb * 16 + quad * 4 + r;
          Kb[((size_t)bh * SEQ_T + trow) * HDIM + nb * 16 + l15] =
              f2bf(acc[mb][nb][r] + bv[nb]);
        }
  }
}

// ---------------------------------------------------------------------------
// Kernel 2 (v5): causal flash attention.
//  - balanced grid: each CU-slot's 4 blocks get qt {31-k,16+k,15-k,k} -> 66
//    tiles per CU exactly; longest-first dispatch order
//  - peeled diagonal tile -> branch-free main loop
//  - l accumulated via 2 extra MFMAs (A = ones): no VALU adds, no shuffles
//  - double-buffered swizzled LDS staging, 1 barrier/tile (r6 scheme)
//  - fixed-shift softmax p = exp2(s-16)
// ---------------------------------------------------------------------------
__global__ __launch_bounds__(256, 4) void attn_mfma5(
    const unsigned short* __restrict__ Qtb, const unsigned short* __restrict__ Kb,
    const unsigned short* __restrict__ Vtb, unsigned short* __restrict__ AOb) {
  __shared__ __align__(16) unsigned short Ks[2][64 * 64];
  __shared__ __align__(16) unsigned short Vs[2][64 * 64];
  __shared__ __align__(16) unsigned short Pt[4][16 * 64];
  const int tid = threadIdx.x;
  const int w = tid >> 6, lane = tid & 63;
  const int quad = lane >> 4, l15 = lane & 15;

  // balanced (bh, qt) mapping
  const int bid = blockIdx.x;
  const int xcd = bid & 7;
  const int j = bid >> 3;            // 0..127
  const int c = j & 31, g = j >> 5;  // CU slot within XCD, co-res slot
  const int k = c >> 2;
  const int bh = xcd + 8 * (c & 3);
  const int qt = (g == 0) ? (31 - k) : (g == 1) ? (16 + k)
               : (g == 2) ? (15 - k) : k;

  const unsigned short* kbase = Kb + (size_t)bh * SEQ_T * HDIM;
  const unsigned short* vbase = Vtb + (size_t)bh * HDIM * SEQ_T;
  const int sr = tid >> 3;             // staging row 0..31
  const int lc = tid & 7;              // logical 16B chunk
  const int scol = lc * 8;
  const int swc = (lc ^ (sr & 7)) * 8; // swizzled slot offset

  // Q B-fragments from transposed Qtb[bh][d][t]: 16 scalar loads, once.
  bf16x8 qf0, qf1;
  {
    unsigned short qraw[16];
    const unsigned short* qp =
        Qtb + ((size_t)bh * HDIM + quad * 8) * SEQ_T + qt * 64 + w * 16 + l15;
#pragma unroll
    for (int jj = 0; jj < 8; ++jj) {
      qraw[jj] = qp[(size_t)jj * SEQ_T];
      qraw[8 + jj] = qp[(size_t)(32 + jj) * SEQ_T];
    }
    qf0 = *(const bf16x8*)qraw;
    qf1 = *(const bf16x8*)(qraw + 8);
  }
  const short oneb = (short)0x3F80;
  const bf16x8 ones = {oneb, oneb, oneb, oneb, oneb, oneb, oneb, oneb};

  f32x4 O[4] = {{0.f, 0.f, 0.f, 0.f}, {0.f, 0.f, 0.f, 0.f},
                {0.f, 0.f, 0.f, 0.f}, {0.f, 0.f, 0.f, 0.f}};
  f32x4 l_acc = {0.f, 0.f, 0.f, 0.f};
  const int q_rel = w * 16 + l15;
  const int r7 = l15 & 7;

  // stage tile 0 into buffer 0
  uint4 rk0, rk1, rv0, rv1;
  {
    const unsigned short* kp = kbase + (size_t)sr * 64 + scol;
    rk0 = *(const uint4*)kp;
    rk1 = *(const uint4*)(kp + 32 * 64);
    const unsigned short* vp = vbase + (size_t)sr * SEQ_T + scol;
    rv0 = *(const uint4*)vp;
    rv1 = *(const uint4*)(vp + 32 * SEQ_T);
  }
  *(uint4*)&Ks[0][sr * 64 + swc] = rk0;
  *(uint4*)&Ks[0][(sr + 32) * 64 + swc] = rk1;
  *(uint4*)&Vs[0][sr * 64 + swc] = rv0;
  *(uint4*)&Vs[0][(sr + 32) * 64 + swc] = rv1;
  __syncthreads();

  // ---- main loop: off-diagonal tiles, branch-free ----
  for (int i = 0; i < qt; ++i) {
    const int cur = i & 1;
    // prefetch tile i+1 (i+1 <= qt always valid)
    {
      const int nkt = i + 1;
      const unsigned short* kp = kbase + (size_t)(nkt * 64 + sr) * 64 + scol;
      rk0 = *(const uint4*)kp;
      rk1 = *(const uint4*)(kp + 32 * 64);
      const unsigned short* vp = vbase + (size_t)sr * SEQ_T + nkt * 64 + scol;
      rv0 = *(const uint4*)vp;
      rv1 = *(const uint4*)(vp + 32 * SEQ_T);
    }

    f32x4 S[4];
#pragma unroll
    for (int nb = 0; nb < 4; ++nb) {
      const int row = nb * 16 + l15;
      const unsigned short* k0p = &Ks[cur][row * 64 + ((quad ^ r7) * 8)];
      const unsigned short* k1p = &Ks[cur][row * 64 + (((quad + 4) ^ r7) * 8)];
      f32x4 z = {0.f, 0.f, 0.f, 0.f};
      z = __builtin_amdgcn_mfma_f32_16x16x32_bf16(*(const bf16x8*)k0p, qf0, z,
                                                  0, 0, 0);
      S[nb] = __builtin_amdgcn_mfma_f32_16x16x32_bf16(*(const bf16x8*)k1p, qf1,
                                                      z, 0, 0, 0);
    }

#pragma unroll
    for (int nb = 0; nb < 4; ++nb) {
      float p0 = __builtin_amdgcn_exp2f(S[nb][0] - SSHIFT);
      float p1 = __builtin_amdgcn_exp2f(S[nb][1] - SSHIFT);
      float p2 = __builtin_amdgcn_exp2f(S[nb][2] - SSHIFT);
      float p3 = __builtin_amdgcn_exp2f(S[nb][3] - SSHIFT);
      int cc = 2 * nb + (quad >> 1);
      uint2 pk = {pack_bf16(p0, p1), pack_bf16(p2, p3)};
      *(uint2*)&Pt[w][l15 * 64 + ((cc ^ r7) * 8) + (quad & 1) * 4] = pk;
    }

    bf16x8 pb0 = *(const bf16x8*)&Pt[w][l15 * 64 + ((quad ^ r7) * 8)];
    bf16x8 pb1 = *(const bf16x8*)&Pt[w][l15 * 64 + (((quad + 4) ^ r7) * 8)];
    l_acc = __builtin_amdgcn_mfma_f32_16x16x32_bf16(ones, pb0, l_acc, 0, 0, 0);
    l_acc = __builtin_amdgcn_mfma_f32_16x16x32_bf16(ones, pb1, l_acc, 0, 0, 0);
#pragma unroll
    for (int nbd = 0; nbd < 4; ++nbd) {
      const int row = nbd * 16 + l15;
      const unsigned short* v0p = &Vs[cur][row * 64 + ((quad ^ r7) * 8)];
      const unsigned short* v1p = &Vs[cur][row * 64 + (((quad + 4) ^ r7) * 8)];
      O[nbd] = __builtin_amdgcn_mfma_f32_16x16x32_bf16(*(const bf16x8*)v0p, pb0,
                                                       O[nbd], 0, 0, 0);
      O[nbd] = __builtin_amdgcn_mfma_f32_16x16x32_bf16(*(const bf16x8*)v1p, pb1,
                                                       O[nbd], 0, 0, 0);
    }

    const int nxt = cur ^ 1;
    *(uint4*)&Ks[nxt][sr * 64 + swc] = rk0;
    *(uint4*)&Ks[nxt][(sr + 32) * 64 + swc] = rk1;
    *(uint4*)&Vs[nxt][sr * 64 + swc] = rv0;
    *(uint4*)&Vs[nxt][(sr + 32) * 64 + swc] = rv1;
    __syncthreads();
  }

  // ---- diagonal tile ----
  {
    const int cur = qt & 1;
    const int nb_lim = w + 1;
    f32x4 S[4];
#pragma unroll
    for (int nb = 0; nb < 4; ++nb) {
      if (nb < nb_lim) {
        const int row = nb * 16 + l15;
        const unsigned short* k0p = &Ks[cur][row * 64 + ((quad ^ r7) * 8)];
        const unsigned short* k1p =
            &Ks[cur][row * 64 + (((quad + 4) ^ r7) * 8)];
        f32x4 z = {0.f, 0.f, 0.f, 0.f};
        z = __builtin_amdgcn_mfma_f32_16x16x32_bf16(*(const bf16x8*)k0p, qf0,
                                                    z, 0, 0, 0);
        S[nb] = __builtin_amdgcn_mfma_f32_16x16x32_bf16(*(const bf16x8*)k1p,
                                                        qf1, z, 0, 0, 0);
      }
    }
#pragma unroll
    for (int nb = 0; nb < 4; ++nb) {
      int cc = 2 * nb + (quad >> 1);
      if (nb < nb_lim) {
        float pp[4];
#pragma unroll
        for (int r = 0; r < 4; ++r) {
          float p = __builtin_amdgcn_exp2f(S[nb][r] - SSHIFT);
          int key_rel = nb * 16 + quad * 4 + r;
          pp[r] = (key_rel > q_rel) ? 0.f : p;
        }
        uint2 pk = {pack_bf16(pp[0], pp[1]), pack_bf16(pp[2], pp[3])};
        *(uint2*)&Pt[w][l15 * 64 + ((cc ^ r7) * 8) + (quad & 1) * 4] = pk;
      } else {
        uint2 z2 = {0u, 0u};
        *(uint2*)&Pt[w][l15 * 64 + ((cc ^ r7) * 8) + (quad & 1) * 4] = z2;
      }
    }
    const int kpv = (w >= 2) ? 2 : 1;
    bf16x8 pb0 = *(const bf16x8*)&Pt[w][l15 * 64 + ((quad ^ r7) * 8)];
    bf16x8 pb1 = *(const bf16x8*)&Pt[w][l15 * 64 + (((quad + 4) ^ r7) * 8)];
    l_acc = __builtin_amdgcn_mfma_f32_16x16x32_bf16(ones, pb0, l_acc, 0, 0, 0);
    if (kpv == 2)
      l_acc =
          __builtin_amdgcn_mfma_f32_16x16x32_bf16(ones, pb1, l_acc, 0, 0, 0);
#pragma unroll
    for (int nbd = 0; nbd < 4; ++nbd) {
      const int row = nbd * 16 + l15;
      const unsigned short* v0p = &Vs[cur][row * 64 + ((quad ^ r7) * 8)];
      O[nbd] = __builtin_amdgcn_mfma_f32_16x16x32_bf16(*(const bf16x8*)v0p, pb0,
                                                       O[nbd], 0, 0, 0);
      if (kpv == 2) {
        const unsigned short* v1p =
            &Vs[cur][row * 64 + (((quad + 4) ^ r7) * 8)];
        O[nbd] = __builtin_amdgcn_mfma_f32_16x16x32_bf16(*(const bf16x8*)v1p,
                                                         pb1, O[nbd], 0, 0, 0);
      }
    }
  }

  // l is identical across the 4 C-rows per lane: no reduction needed.
  float inv = 1.0f / l_acc[0];
  const int bb = bh >> 3, h = bh & 7;
  int qrow = qt * 64 + q_rel;
  unsigned short* dst = AOb + ((size_t)bb * SEQ_T + qrow) * D_MODEL + (h << 6);
#pragma unroll
  for (int nbd = 0; nbd < 4; ++nbd) {
    ushort4 o4 = {f2bf(O[nbd][0] * inv), f2bf(O[nbd][1] * inv),
                  f2bf(O[nbd][2] * inv), f2bf(O[nbd][3] * inv)};
    *(ushort4*)(dst + nbd * 16 + quad * 4) = o4;
  }
}

// ---------------------------------------------------------------------------
// Kernel 3: output projection, bf16 MFMA. 64x128 tile (512 blocks, 2/CU),
// BK=64 swizzled. AOb[8192][512] @ Wot[512][512]^T + b -> fp32 out.
// ---------------------------------------------------------------------------
__global__ __launch_bounds__(256) void gemm_out_mfma(
    const unsigned short* __restrict__ AOb, const unsigned short* __restrict__ Wot,
    const float* __restrict__ bias, float* __restrict__ out) {
  __shared__ unsigned short As[64 * 64];
  __shared__ unsigned short Bs[128 * 64];
  const int tid = threadIdx.x;
  const int w = tid >> 6, lane = tid & 63;
  const int quad = lane >> 4, l15 = lane & 15;
  const int m0 = blockIdx.x * 64, n0 = blockIdx.y * 128;

  const int srow = tid >> 3;
  const int schunk = (tid & 7) ^ (srow & 7);
  const unsigned short* ga = AOb + (size_t)(m0 + srow) * 512 + schunk * 8;
  const unsigned short* gb = Wot + (size_t)(n0 + srow) * 512 + schunk * 8;
  unsigned short* lA = As + tid * 8;
  unsigned short* lB = Bs + tid * 8;

  f32x4 acc[4][2] = {};
  for (int k0 = 0; k0 < 512; k0 += 64) {
#pragma unroll
    for (int rr = 0; rr < 2; ++rr)
      async_lds16(ga + (size_t)rr * 32 * 512 + k0, lA + rr * 2048);
#pragma unroll
    for (int rr = 0; rr < 4; ++rr)
      async_lds16(gb + (size_t)rr * 32 * 512 + k0, lB + rr * 2048);
    __syncthreads();
    bf16x8 af[4][2], bfr[2][2];
#pragma unroll
    for (int mb = 0; mb < 4; ++mb) {
      int row = mb * 16 + l15;
#pragma unroll
      for (int kk = 0; kk < 2; ++kk) {
        int slot = (kk * 4 + quad) ^ (row & 7);
        af[mb][kk] = *(const bf16x8*)&As[row * 64 + slot * 8];
      }
    }
#pragma unroll
    for (int nb = 0; nb < 2; ++nb) {
      int row = w * 32 + nb * 16 + l15;
#pragma unroll
      for (int kk = 0; kk < 2; ++kk) {
        int slot = (kk * 4 + quad) ^ (row & 7);
        bfr[nb][kk] = *(const bf16x8*)&Bs[row * 64 + slot * 8];
      }
    }
#pragma unroll
    for (int mb = 0; mb < 4; ++mb)
#pragma unroll
      for (int nb = 0; nb < 2; ++nb) {
        acc[mb][nb] = __builtin_amdgcn_mfma_f32_16x16x32_bf16(
            af[mb][0], bfr[nb][0], acc[mb][nb], 0, 0, 0);
        acc[mb][nb] = __builtin_amdgcn_mfma_f32_16x16x32_bf16(
            af[mb][1], bfr[nb][1], acc[mb][nb], 0, 0, 0);
      }
    __syncthreads();
  }

  const int cbase = n0 + w * 32;
  float bv[2];
#pragma unroll
  for (int nb = 0; nb < 2; ++nb) bv[nb] = bias[cbase + nb * 16 + l15];
#pragma unroll
  for (int mb = 0; mb < 4; ++mb)
#pragma unroll
    for (int nb = 0; nb < 2; ++nb)
#pragma unroll
      for (int r = 0; r < 4; ++r)
        out[(size_t)(m0 + mb * 16 + quad * 4 + r) * 512 + cbase + nb * 16 +
            l15] = acc[mb][nb][r] + bv[nb];
}

// ---------------------------------------------------------------------------
extern "C" void kernel_launch(void* const* d_in, const int* in_sizes, int n_in,
                              void* d_out, int out_size, void* d_ws,
                              size_t ws_size, hipStream_t stream) {
  const float* x     = (const float*)d_in[0];
  const float* W_qkv = (const float*)d_in[1];
  const float* b_qkv = (const float*)d_in[2];
  const float* W_out = (const float*)d_in[3];
  const float* b_out = (const float*)d_in[4];
  float* out = (float*)d_out;

  const size_t NX = (size_t)4 * SEQ_T * D_MODEL;        // 4,194,304
  unsigned short* xb   = (unsigned short*)d_ws;          // [8192][512]
  unsigned short* Wqkt = xb + NX;                        // [1536][512]
  unsigned short* Wot  = Wqkt + (size_t)1536 * 512;      // [512][512]
  unsigned short* Qtb  = Wot + (size_t)512 * 512;        // [bh][d][t]
  unsigned short* Kb   = Qtb + NX;                       // [bh][t][d]
  unsigned short* Vtb  = Kb + NX;                        // [bh][dv][t]
  unsigned short* AOb  = Vtb + NX;                       // [8192][512]

  prep_kernel<<<2304, 256, 0, stream>>>(x, W_qkv, W_out, xb, Wqkt, Wot);
  gemm_qkv_mfma<<<dim3(64, 12), 256, 0, stream>>>(xb, Wqkt, b_qkv, Qtb, Kb,
                                                  Vtb);
  attn_mfma5<<<dim3(1024), 256, 0, stream>>>(Qtb, Kb, Vtb, AOb);
  gemm_out_mfma<<<dim3(128, 4), 256, 0, stream>>>(AOb, Wot, b_out, out);
}